// Round 3
// baseline (292.207 us; speedup 1.0000x reference)
//
#include <hip/hip_runtime.h>
#include <hip/hip_bf16.h>
#include <stdint.h>

// DCNv2 forward, fixed shapes: N=8, Cin=Cout=256, H=W=Ho=Wo=64, K=3x3, DG=1,
// stride=1, pad=1, dil=1.
//
// R6: producer/consumer wave specialization. R5 post-mortem: with all waves
// running gather->bilerp->MFMA in the same program order, the per-tap barrier
// re-aligns every wave so all 16 resident waves stall on gathers at the same
// time -- no wave is ever in the MFMA section to co-issue with (m114 overlap
// needs the phases in DIFFERENT waves). Fix: waves 0-3 sample tap k+1 into
// colF[nxt] (gather+bilerp+ds_write); waves 4-7 run tap k's 8 MFMA K-steps
// from colF[cur] with acc[4][4] (4 m-tiles each). One barrier per tap, all
// barriers wave-uniform and outside the role branch. Producer items process a
// channel-granule PAIR (32B/corner) to halve gather addressing VALU.

#define XH 64
#define XW 64
#define CIN 256
#define COUT 256
#define NK 9

typedef __attribute__((ext_vector_type(8))) short short8;   // 8 bf16 (4 VGPRs)
typedef __attribute__((ext_vector_type(4))) float floatx4;
typedef __attribute__((ext_vector_type(2))) float floatx2;
typedef __attribute__((ext_vector_type(4))) int   intx4;

__device__ __forceinline__ short f32_to_bf16_rne(float f) {
    union { float f; uint32_t u; } v; v.f = f;
    uint32_t u = v.u;
    uint32_t r = (u + 0x7FFFu + ((u >> 16) & 1u)) >> 16;
    return (short)(uint16_t)r;
}
__device__ __forceinline__ float bf16_to_f32(short s) {
    union { uint32_t u; float f; } v;
    v.u = ((uint32_t)(uint16_t)s) << 16;
    return v.f;
}
__device__ __forceinline__ floatx2 bf16x2_to_f32x2(uint32_t u) {
    union { uint32_t u; float f; } lo, hi;
    lo.u = u << 16;
    hi.u = u & 0xFFFF0000u;
    floatx2 r; r.x = lo.f; r.y = hi.f;
    return r;
}

union U8 { short8 s; uint32_t u[4]; };

// ---------------------------------------------------------------------------
// Combined prep (unchanged from R3).
// Blocks [0,512): x (N,C,H,W) f32 -> xT (N,H,W,C) bf16, XCD-swizzled so the
//   XCD that writes rows [8x,8x+8) is the one that reads them in dcn_fused6.
// Blocks [512,800): weight swizzle -> w3 (bf16), 8 elems/thread.
//   w3[(((k*8+ks)*16+mt)*64+lane)*8+j] = W[mt*16+(lane&15)][ks*32+(lane>>4)*8+j][k]
__global__ void dcn_prep(const float* __restrict__ x, const float* __restrict__ w,
                         short* __restrict__ xT, short* __restrict__ w3) {
    int b = blockIdx.x;
    int tid = threadIdx.x;
    if (b < 512) {
        int xcd = b & 7, slot = b >> 3;
        int h = xcd * 8 + (slot & 7);
        int n = slot >> 3;
        int q = tid & 15;        // w-quad
        int cgh = tid >> 4;      // 0..15
        short8* ob = (short8*)(xT + ((size_t)(n * XH + h)) * (XW * CIN));
        for (int it = 0; it < 2; ++it) {
            int cg = cgh + it * 16;          // channel granule 0..31
            const float* xb = x + ((size_t)(n * CIN + cg * 8)) * (XH * XW)
                                + h * XW + q * 4;
            floatx4 r[8];
#pragma unroll
            for (int j = 0; j < 8; ++j)
                r[j] = *(const floatx4*)(xb + (size_t)j * (XH * XW));
#pragma unroll
            for (int jw = 0; jw < 4; ++jw) {
                short8 pk;
#pragma unroll
                for (int j = 0; j < 8; ++j) pk[j] = f32_to_bf16_rne(r[j][jw]);
                ob[(q * 4 + jw) * 32 + cg] = pk;
            }
        }
    } else {
        int gidx = (b - 512) * 256 + tid;    // granule index, < 73728
        int lane = gidx & 63;
        int mt   = (gidx >> 6) & 15;
        int t    = gidx >> 10;               // k*8 + ks
        int ks   = t & 7;
        int k    = t >> 3;
        int co = mt * 16 + (lane & 15);
        int c0 = ks * 32 + (lane >> 4) * 8;
        short8 pk;
#pragma unroll
        for (int j = 0; j < 8; ++j)
            pk[j] = f32_to_bf16_rne(w[(co * CIN + c0 + j) * NK + k]);
        *(short8*)&w3[(size_t)gidx * 8] = pk;
    }
}

// ---------------------------------------------------------------------------
// Producer/consumer fused kernel. grid = N*Ho = 512, 512 threads (8 waves),
// XCD-swizzled. Waves 0-3 produce colF[nxt]; waves 4-7 consume colF[cur].
__launch_bounds__(512, 4)
__global__ void dcn_fused6(const short* __restrict__ xT,
                           const float* __restrict__ off,
                           const float* __restrict__ msk,
                           const short* __restrict__ w3,
                           const float* __restrict__ bias,
                           float* __restrict__ out) {
    // per buffer: 2048 granules of 16B; granule(chg,pos) at
    // g = chg*64 + (pos ^ (chg & 7))  -- same swizzle as R3 (0 conflicts)
    __shared__ short   colF[2][2048 * 8];    // 2 x 32768 B
    __shared__ floatx4 pairW[576];           //  9216 B
    __shared__ ushort4 pairO[576];           //  4608 B (raw spatial offs)

    const int bid = blockIdx.x;
    const int xcd = bid & 7, slot = bid >> 3;
    const int ho = xcd * 8 + (slot & 7);     // XCD x owns ho band [8x, 8x+8)
    const int n  = slot >> 3;
    const int tid  = threadIdx.x;
    const int wave = tid >> 6;
    const int lane = tid & 63;
    const int quad = lane >> 4, cl = lane & 15;

    // ---- bilinear params for 576 (wo, tap) pairs (mask folded into weights).
    for (int p = tid; p < 576; p += 512) {
        int wo = p & 63, k = p >> 6;
        int obase = ((n * 18 + 2 * k) * XH + ho) * XW + wo;
        float dy = off[obase];
        float dx = off[obase + XH * XW];
        float mm = msk[((n * NK + k) * XH + ho) * XW + wo];
        float y  = (float)(ho - 1 + k / 3) + dy;
        float xs = (float)(wo - 1 + k % 3) + dx;
        float y0f = floorf(y), x0f = floorf(xs);
        float fy = y - y0f, fx = xs - x0f;
        int y0 = (int)y0f, x0 = (int)x0f;
        float vy0 = (y0 >= 0  && y0 < XH)     ? 1.f : 0.f;
        float vy1 = (y0 >= -1 && y0 < XH - 1) ? 1.f : 0.f;
        float vx0 = (x0 >= 0  && x0 < XW)     ? 1.f : 0.f;
        float vx1 = (x0 >= -1 && x0 < XW - 1) ? 1.f : 0.f;
        floatx4 wv;
        wv.x = (1.f - fy) * (1.f - fx) * mm * vy0 * vx0;
        wv.y = (1.f - fy) * fx         * mm * vy0 * vx1;
        wv.z = fy         * (1.f - fx) * mm * vy1 * vx0;
        wv.w = fy         * fx         * mm * vy1 * vx1;
        int y0c = min(max(y0, 0), XH - 1), y1c = min(max(y0 + 1, 0), XH - 1);
        int x0c = min(max(x0, 0), XW - 1), x1c = min(max(x0 + 1, 0), XW - 1);
        ushort4 ov;
        ov.x = (unsigned short)(y0c * XW + x0c);
        ov.y = (unsigned short)(y0c * XW + x1c);
        ov.z = (unsigned short)(y1c * XW + x0c);
        ov.w = (unsigned short)(y1c * XW + x1c);
        pairW[p] = wv;
        pairO[p] = ov;
    }
    __syncthreads();

    const short8* xTv = (const short8*)(xT + (size_t)n * (XH * XW * CIN));
    const short8* w3v = (const short8*)w3;

    // Producer: gather + bilerp + LDS-write for one whole tap. 256 threads,
    // item = (pos, chg-pair): 2 adjacent 16B granules per corner (32B runs,
    // one address calc per corner pair). 16 lanes x 32B = 512B contiguous
    // per (pos, corner).
    auto sampleTap = [&](int k, short* dst) {
        for (int it = 0; it < 4; ++it) {
            int idx = it * 256 + tid;        // tid in [0,256) for producers
            int cp  = idx & 15;              // chg pair 0..15
            int pos = idx >> 4;              // 0..63
            int p = k * 64 + pos;
            floatx4 wv = pairW[p];
            ushort4 ov = pairO[p];
            int c0 = cp * 2;
            const short8* q00 = xTv + ((size_t)((int)ov.x * 32 + c0));
            const short8* q01 = xTv + ((size_t)((int)ov.y * 32 + c0));
            const short8* q10 = xTv + ((size_t)((int)ov.z * 32 + c0));
            const short8* q11 = xTv + ((size_t)((int)ov.w * 32 + c0));
            U8 s00[2], s01[2], s10[2], s11[2];
            s00[0].s = q00[0]; s00[1].s = q00[1];
            s01[0].s = q01[0]; s01[1].s = q01[1];
            s10[0].s = q10[0]; s10[1].s = q10[1];
            s11[0].s = q11[0]; s11[1].s = q11[1];
            U8 pk0, pk1;
#pragma unroll
            for (int i = 0; i < 4; ++i) {
                floatx2 v0 = bf16x2_to_f32x2(s00[0].u[i]) * wv.x
                           + bf16x2_to_f32x2(s01[0].u[i]) * wv.y
                           + bf16x2_to_f32x2(s10[0].u[i]) * wv.z
                           + bf16x2_to_f32x2(s11[0].u[i]) * wv.w;
                floatx2 v1 = bf16x2_to_f32x2(s00[1].u[i]) * wv.x
                           + bf16x2_to_f32x2(s01[1].u[i]) * wv.y
                           + bf16x2_to_f32x2(s10[1].u[i]) * wv.z
                           + bf16x2_to_f32x2(s11[1].u[i]) * wv.w;
                float2 f0; f0.x = v0.x; f0.y = v0.y;
                float2 f1; f1.x = v1.x; f1.y = v1.y;
                __hip_bfloat162 h0 = __float22bfloat162_rn(f0);
                __hip_bfloat162 h1 = __float22bfloat162_rn(f1);
                __builtin_memcpy(&pk0.u[i], &h0, 4);
                __builtin_memcpy(&pk1.u[i], &h1, 4);
            }
            int g0 = c0 * 64 + (pos ^ (c0 & 7));
            int g1 = (c0 + 1) * 64 + (pos ^ ((c0 + 1) & 7));
            *(short8*)&dst[g0 * 8] = pk0.s;
            *(short8*)&dst[g1 * 8] = pk1.s;
        }
    };

    floatx4 acc[4][4];
#pragma unroll
    for (int mt = 0; mt < 4; ++mt)
#pragma unroll
        for (int nt = 0; nt < 4; ++nt)
            acc[mt][nt] = (floatx4)(0.f);
    const int ci = wave - 4;                 // consumer index 0..3

    // ---- prologue: producers fill tap 0 ----
    if (wave < 4) sampleTap(0, colF[0]);
    __syncthreads();

    short* cur = colF[0];
    short* nxt = colF[1];
#pragma unroll 1
    for (int k = 0; k < NK; ++k) {
        if (wave < 4) {
            // PRODUCER: sample tap k+1 (consumers are reading cur, we write nxt)
            if (k < NK - 1) sampleTap(k + 1, nxt);
        } else {
            // CONSUMER: 8 K-steps of 32 channels from cur; 4 m-tiles each
            const short8* cb = (const short8*)cur;
            for (int ks = 0; ks < 8; ++ks) {
                short8 bfrag[4];
                int cr = ks * 4 + quad;      // chg being read
                int gb = cr * 64, sw = cr & 7;
#pragma unroll
                for (int nt = 0; nt < 4; ++nt)
                    bfrag[nt] = cb[gb + ((nt * 16 + cl) ^ sw)];
#pragma unroll
                for (int mt = 0; mt < 4; ++mt) {
                    short8 afrag =
                        w3v[(((k * 8 + ks) * 16) + (ci * 4 + mt)) * 64 + lane];
#pragma unroll
                    for (int nt = 0; nt < 4; ++nt)
                        acc[mt][nt] = __builtin_amdgcn_mfma_f32_16x16x32_bf16(
                            afrag, bfrag[nt], acc[mt][nt], 0, 0, 0);
                }
            }
        }
        __syncthreads();
        short* t = cur; cur = nxt; nxt = t;
    }

    // ---- epilogue (consumers): D layout col=lane&15 (pos), row=(lane>>4)*4+reg
    if (wave >= 4) {
#pragma unroll
        for (int mt = 0; mt < 4; ++mt) {
            int cobase = (ci * 4 + mt) * 16 + quad * 4;
#pragma unroll
            for (int r = 0; r < 4; ++r) {
                int co = cobase + r;
                float b = bias[co];
                float* op = out + (((size_t)n * COUT + co) * XH + ho) * XW;
#pragma unroll
                for (int nt = 0; nt < 4; ++nt)
                    op[nt * 16 + cl] = acc[mt][nt][r] + b;
            }
        }
    }
}

// ===========================================================================
// Fallback 1 (ws in [1.18MB, 18MB)): round-1 fused kernel (NCHW gathers).
__global__ void dcn_wprep_v1(const float* __restrict__ w, short* __restrict__ w3) {
    int idx = blockIdx.x * 256 + threadIdx.x;
    if (idx >= 8 * 9 * 16 * 64 * 8) return;
    int j    = idx & 7;
    int lane = (idx >> 3) & 63;
    int mt   = (idx >> 9) & 15;
    int t    = idx >> 13;
    int ks   = t % 9;
    int cc   = t / 9;
    int co = mt * 16 + (lane & 15);
    int c  = cc * 32 + (lane >> 4) * 8 + j;
    w3[idx] = f32_to_bf16_rne(w[(co * CIN + c) * NK + ks]);
}

__launch_bounds__(256, 2)
__global__ void dcn_fused_v1(const float* __restrict__ x,
                             const float* __restrict__ off,
                             const float* __restrict__ msk,
                             const short* __restrict__ w3,
                             const float* __restrict__ bias,
                             float* __restrict__ out) {
    __shared__ short  colF[2304 * 8];
    __shared__ floatx4 pairW[576];
    __shared__ intx4   pairO[576];

    const int bid = blockIdx.x;
    const int n  = bid >> 6;
    const int ho = bid & 63;
    const int tid  = threadIdx.x;
    const int wave = tid >> 6;
    const int lane = tid & 63;

    for (int p = tid; p < 576; p += 256) {
        int wo = p & 63, k = p >> 6;
        int obase = ((n * 18 + 2 * k) * XH + ho) * XW + wo;
        float dy = off[obase];
        float dx = off[obase + XH * XW];
        float mm = msk[((n * NK + k) * XH + ho) * XW + wo];
        float y  = (float)(ho - 1 + k / 3) + dy;
        float xs = (float)(wo - 1 + k % 3) + dx;
        float y0f = floorf(y), x0f = floorf(xs);
        float fy = y - y0f, fx = xs - x0f;
        int y0 = (int)y0f, x0 = (int)x0f;
        float vy0 = (y0 >= 0  && y0 < XH)     ? 1.f : 0.f;
        float vy1 = (y0 >= -1 && y0 < XH - 1) ? 1.f : 0.f;
        float vx0 = (x0 >= 0  && x0 < XW)     ? 1.f : 0.f;
        float vx1 = (x0 >= -1 && x0 < XW - 1) ? 1.f : 0.f;
        floatx4 wv;
        wv.x = (1.f - fy) * (1.f - fx) * mm * vy0 * vx0;
        wv.y = (1.f - fy) * fx         * mm * vy0 * vx1;
        wv.z = fy         * (1.f - fx) * mm * vy1 * vx0;
        wv.w = fy         * fx         * mm * vy1 * vx1;
        int y0c = min(max(y0, 0), XH - 1), y1c = min(max(y0 + 1, 0), XH - 1);
        int x0c = min(max(x0, 0), XW - 1), x1c = min(max(x0 + 1, 0), XW - 1);
        intx4 ov;
        ov.x = y0c * XW + x0c; ov.y = y0c * XW + x1c;
        ov.z = y1c * XW + x0c; ov.w = y1c * XW + x1c;
        pairW[p] = wv;
        pairO[p] = ov;
    }
    __syncthreads();

    floatx4 acc[4][4];
#pragma unroll
    for (int mt = 0; mt < 4; ++mt)
#pragma unroll
        for (int nt = 0; nt < 4; ++nt)
            acc[mt][nt] = (floatx4)(0.f);

    const float* xn = x + (size_t)n * CIN * (XH * XW);
    const short8* w3v = (const short8*)w3;

    for (int cc = 0; cc < 8; ++cc) {
        __syncthreads();
        for (int it = 0; it < 9; ++it) {
            int item = it * 256 + tid;
            int pos  = item & 63;
            int r    = item >> 6;
            int k    = r >> 2;
            int csub = r & 3;
            int p = k * 64 + pos;
            floatx4 wv = pairW[p];
            intx4   ov = pairO[p];
            const float* xc = xn + (size_t)(cc * 32 + csub * 8) * (XH * XW);
            short8 pk;
#pragma unroll
            for (int i = 0; i < 8; ++i) {
                const float* xp = xc + i * (XH * XW);
                float v = wv.x * xp[ov.x] + wv.y * xp[ov.y] +
                          wv.z * xp[ov.z] + wv.w * xp[ov.w];
                pk[i] = f32_to_bf16_rne(v);
            }
            *(short8*)&colF[(((k * 4 + csub) * 64) + pos) * 8] = pk;
        }
        __syncthreads();

        const int quad = lane >> 4, cl = lane & 15;
        for (int ks = 0; ks < 9; ++ks) {
            short8 afrag[4];
#pragma unroll
            for (int mt = 0; mt < 4; ++mt) {
                int mtg = wave * 4 + mt;
                afrag[mt] = w3v[(((cc * 9 + ks) * 16 + mtg) * 64) + lane];
            }
            short8 bfrag[4];
#pragma unroll
            for (int nt = 0; nt < 4; ++nt)
                bfrag[nt] = *(const short8*)
                    &colF[(((ks * 4 + quad) * 64) + nt * 16 + cl) * 8];
#pragma unroll
            for (int mt = 0; mt < 4; ++mt)
#pragma unroll
                for (int nt = 0; nt < 4; ++nt)
                    acc[mt][nt] = __builtin_amdgcn_mfma_f32_16x16x32_bf16(
                        afrag[mt], bfrag[nt], acc[mt][nt], 0, 0, 0);
        }
    }

    const int quad = lane >> 4, cl = lane & 15;
#pragma unroll
    for (int mt = 0; mt < 4; ++mt) {
        int cobase = (wave * 4 + mt) * 16 + quad * 4;
#pragma unroll
        for (int r = 0; r < 4; ++r) {
            int co = cobase + r;
            float b = bias[co];
            float* op = out + (((size_t)n * COUT + co) * XH + ho) * XW;
#pragma unroll
            for (int nt = 0; nt < 4; ++nt)
                op[nt * 16 + cl] = acc[mt][nt][r] + b;
        }
    }
}

// Fallback 2: naive (ws < 1.18MB).
__global__ void dcn_naive(const float* __restrict__ x,
                          const float* __restrict__ off,
                          const float* __restrict__ msk,
                          const float* __restrict__ w,
                          const float* __restrict__ bias,
                          float* __restrict__ out) {
    int idx = blockIdx.x * 256 + threadIdx.x;
    if (idx >= 8 * COUT * XH * XW) return;
    int wo = idx & 63, ho = (idx >> 6) & 63, co = (idx >> 12) & 255, n = idx >> 20;
    float acc = bias[co];
    for (int k = 0; k < NK; ++k) {
        int obase = ((n * 18 + 2 * k) * XH + ho) * XW + wo;
        float dy = off[obase];
        float dx = off[obase + XH * XW];
        float mm = msk[((n * NK + k) * XH + ho) * XW + wo];
        float y  = (float)(ho - 1 + k / 3) + dy;
        float xs = (float)(wo - 1 + k % 3) + dx;
        float y0f = floorf(y), x0f = floorf(xs);
        float fy = y - y0f, fx = xs - x0f;
        int y0 = (int)y0f, x0 = (int)x0f;
        float vy0 = (y0 >= 0  && y0 < XH)     ? 1.f : 0.f;
        float vy1 = (y0 >= -1 && y0 < XH - 1) ? 1.f : 0.f;
        float vx0 = (x0 >= 0  && x0 < XW)     ? 1.f : 0.f;
        float vx1 = (x0 >= -1 && x0 < XW - 1) ? 1.f : 0.f;
        float w00 = (1.f - fy) * (1.f - fx) * mm * vy0 * vx0;
        float w01 = (1.f - fy) * fx         * mm * vy0 * vx1;
        float w10 = fy         * (1.f - fx) * mm * vy1 * vx0;
        float w11 = fy         * fx         * mm * vy1 * vx1;
        int y0c = min(max(y0, 0), XH - 1), y1c = min(max(y0 + 1, 0), XH - 1);
        int x0c = min(max(x0, 0), XW - 1), x1c = min(max(x0 + 1, 0), XW - 1);
        int o00 = y0c * XW + x0c, o01 = y0c * XW + x1c;
        int o10 = y1c * XW + x0c, o11 = y1c * XW + x1c;
        for (int c = 0; c < CIN; ++c) {
            const float* xp = x + ((size_t)(n * CIN + c)) * (XH * XW);
            float v = w00 * xp[o00] + w01 * xp[o01] + w10 * xp[o10] + w11 * xp[o11];
            acc += v * w[(co * CIN + c) * NK + k];
        }
    }
    out[idx] = acc;
}

// ---------------------------------------------------------------------------
extern "C" void kernel_launch(void* const* d_in, const int* in_sizes, int n_in,
                              void* d_out, int out_size, void* d_ws, size_t ws_size,
                              hipStream_t stream) {
    const float* x    = (const float*)d_in[0];
    const float* off  = (const float*)d_in[1];
    const float* msk  = (const float*)d_in[2];
    const float* w    = (const float*)d_in[3];
    const float* bias = (const float*)d_in[4];
    float* out = (float*)d_out;

    const size_t W3_BYTES = (size_t)9 * 8 * 16 * 64 * 8 * sizeof(short); // 1179648
    const size_t XT_BYTES = (size_t)8 * XH * XW * CIN * sizeof(short);   // 16777216

    if (ws_size >= W3_BYTES + XT_BYTES) {
        short* w3 = (short*)d_ws;
        short* xT = (short*)((char*)d_ws + W3_BYTES);
        dcn_prep<<<512 + 288, 256, 0, stream>>>(x, w, xT, w3);
        dcn_fused6<<<8 * 64, 512, 0, stream>>>(xT, off, msk, w3, bias, out);
    } else if (ws_size >= W3_BYTES) {
        short* w3 = (short*)d_ws;
        dcn_wprep_v1<<<(8 * 9 * 16 * 64 * 8 + 255) / 256, 256, 0, stream>>>(w, w3);
        dcn_fused_v1<<<8 * 64, 256, 0, stream>>>(x, off, msk, w3, bias, out);
    } else {
        dcn_naive<<<(8 * COUT * XH * XW + 255) / 256, 256, 0, stream>>>(
            x, off, msk, w, bias, out);
    }
}

// Round 4
// 171.848 us; speedup vs baseline: 1.7004x; 1.7004x over previous
//
#include <hip/hip_runtime.h>
#include <hip/hip_bf16.h>
#include <stdint.h>

// DCNv2 forward, fixed shapes: N=8, Cin=Cout=256, H=W=Ho=Wo=64, K=3x3, DG=1,
// stride=1, pad=1, dil=1.
//
// R7: intra-wave ILP pipeline. Session ledger:
//   R4 (reg-stage 2 items across MFMA): spilled at the 128-reg unified cap.
//   R5 (same-wave A->B, 1 barrier): barrier re-aligns waves; no overlap.
//   R6 (producer/consumer waves): regalloc is STATIC -> producers carry the
//       consumers' 64 dead acc AGPRs and spill; producer-side also starved.
// Surviving mechanism: ONE gather item (16 VGPR) in flight at a time,
// interleaved with 2 MFMA K-steps (AITER-style 1:1 interleave). ISSUE fires
// the 4 corner loads; 2 K-steps (~250cyc LDS+MFMA) hide the L2 latency;
// FINISH does bilerp (VALU co-issues against matrix pipe) + ds_write to the
// other colF buffer. One barrier per tap. Gather layout identical to R3
// (512B contiguous runs). Buffers ping-pong via compile-time pointers.

#define XH 64
#define XW 64
#define CIN 256
#define COUT 256
#define NK 9

typedef __attribute__((ext_vector_type(8))) short short8;   // 8 bf16 (4 VGPRs)
typedef __attribute__((ext_vector_type(4))) float floatx4;
typedef __attribute__((ext_vector_type(2))) float floatx2;
typedef __attribute__((ext_vector_type(4))) int   intx4;

__device__ __forceinline__ short f32_to_bf16_rne(float f) {
    union { float f; uint32_t u; } v; v.f = f;
    uint32_t u = v.u;
    uint32_t r = (u + 0x7FFFu + ((u >> 16) & 1u)) >> 16;
    return (short)(uint16_t)r;
}
__device__ __forceinline__ float bf16_to_f32(short s) {
    union { uint32_t u; float f; } v;
    v.u = ((uint32_t)(uint16_t)s) << 16;
    return v.f;
}
__device__ __forceinline__ floatx2 bf16x2_to_f32x2(uint32_t u) {
    union { uint32_t u; float f; } lo, hi;
    lo.u = u << 16;
    hi.u = u & 0xFFFF0000u;
    floatx2 r; r.x = lo.f; r.y = hi.f;
    return r;
}

union U8 { short8 s; uint32_t u[4]; };

// ---------------------------------------------------------------------------
// Combined prep (unchanged from R3).
__global__ void dcn_prep(const float* __restrict__ x, const float* __restrict__ w,
                         short* __restrict__ xT, short* __restrict__ w3) {
    int b = blockIdx.x;
    int tid = threadIdx.x;
    if (b < 512) {
        int xcd = b & 7, slot = b >> 3;
        int h = xcd * 8 + (slot & 7);
        int n = slot >> 3;
        int q = tid & 15;        // w-quad
        int cgh = tid >> 4;      // 0..15
        short8* ob = (short8*)(xT + ((size_t)(n * XH + h)) * (XW * CIN));
        for (int it = 0; it < 2; ++it) {
            int cg = cgh + it * 16;          // channel granule 0..31
            const float* xb = x + ((size_t)(n * CIN + cg * 8)) * (XH * XW)
                                + h * XW + q * 4;
            floatx4 r[8];
#pragma unroll
            for (int j = 0; j < 8; ++j)
                r[j] = *(const floatx4*)(xb + (size_t)j * (XH * XW));
#pragma unroll
            for (int jw = 0; jw < 4; ++jw) {
                short8 pk;
#pragma unroll
                for (int j = 0; j < 8; ++j) pk[j] = f32_to_bf16_rne(r[j][jw]);
                ob[(q * 4 + jw) * 32 + cg] = pk;
            }
        }
    } else {
        int gidx = (b - 512) * 256 + tid;    // granule index, < 73728
        int lane = gidx & 63;
        int mt   = (gidx >> 6) & 15;
        int t    = gidx >> 10;               // k*8 + ks
        int ks   = t & 7;
        int k    = t >> 3;
        int co = mt * 16 + (lane & 15);
        int c0 = ks * 32 + (lane >> 4) * 8;
        short8 pk;
#pragma unroll
        for (int j = 0; j < 8; ++j)
            pk[j] = f32_to_bf16_rne(w[(co * CIN + c0 + j) * NK + k]);
        *(short8*)&w3[(size_t)gidx * 8] = pk;
    }
}

// ---------------------------------------------------------------------------
// Interleaved fused kernel. grid = N*Ho = 512, 512 threads (8 waves),
// XCD-swizzled. One barrier per tap; gathers for tap k+1 interleaved with
// tap k's MFMA at 2-K-step granularity; one item (16 VGPR) in flight.
__launch_bounds__(512, 4)
__global__ void dcn_fused7(const short* __restrict__ xT,
                           const float* __restrict__ off,
                           const float* __restrict__ msk,
                           const short* __restrict__ w3,
                           const float* __restrict__ bias,
                           float* __restrict__ out) {
    // per buffer: 2048 granules of 16B; granule(chg,pos) at
    // g = chg*64 + (pos ^ (chg & 7))  -- same swizzle as R3 (0 conflicts)
    __shared__ short   colF[2][2048 * 8];    // 2 x 32768 B
    __shared__ floatx4 pairW[576];           //  9216 B
    __shared__ ushort4 pairO[576];           //  4608 B (raw spatial offs)

    const int bid = blockIdx.x;
    const int xcd = bid & 7, slot = bid >> 3;
    const int ho = xcd * 8 + (slot & 7);     // XCD x owns ho band [8x, 8x+8)
    const int n  = slot >> 3;
    const int tid  = threadIdx.x;
    const int wave = tid >> 6;
    const int lane = tid & 63;
    const int quad = lane >> 4, cl = lane & 15;

    // ---- bilinear params for 576 (wo, tap) pairs (mask folded into weights).
    for (int p = tid; p < 576; p += 512) {
        int wo = p & 63, k = p >> 6;
        int obase = ((n * 18 + 2 * k) * XH + ho) * XW + wo;
        float dy = off[obase];
        float dx = off[obase + XH * XW];
        float mm = msk[((n * NK + k) * XH + ho) * XW + wo];
        float y  = (float)(ho - 1 + k / 3) + dy;
        float xs = (float)(wo - 1 + k % 3) + dx;
        float y0f = floorf(y), x0f = floorf(xs);
        float fy = y - y0f, fx = xs - x0f;
        int y0 = (int)y0f, x0 = (int)x0f;
        float vy0 = (y0 >= 0  && y0 < XH)     ? 1.f : 0.f;
        float vy1 = (y0 >= -1 && y0 < XH - 1) ? 1.f : 0.f;
        float vx0 = (x0 >= 0  && x0 < XW)     ? 1.f : 0.f;
        float vx1 = (x0 >= -1 && x0 < XW - 1) ? 1.f : 0.f;
        floatx4 wv;
        wv.x = (1.f - fy) * (1.f - fx) * mm * vy0 * vx0;
        wv.y = (1.f - fy) * fx         * mm * vy0 * vx1;
        wv.z = fy         * (1.f - fx) * mm * vy1 * vx0;
        wv.w = fy         * fx         * mm * vy1 * vx1;
        int y0c = min(max(y0, 0), XH - 1), y1c = min(max(y0 + 1, 0), XH - 1);
        int x0c = min(max(x0, 0), XW - 1), x1c = min(max(x0 + 1, 0), XW - 1);
        ushort4 ov;
        ov.x = (unsigned short)(y0c * XW + x0c);
        ov.y = (unsigned short)(y0c * XW + x1c);
        ov.z = (unsigned short)(y1c * XW + x0c);
        ov.w = (unsigned short)(y1c * XW + x1c);
        pairW[p] = wv;
        pairO[p] = ov;
    }
    __syncthreads();

    floatx4 acc[2][4];
#pragma unroll
    for (int mt = 0; mt < 2; ++mt)
#pragma unroll
        for (int nt = 0; nt < 4; ++nt)
            acc[mt][nt] = (floatx4)(0.f);

    const short8* xTv = (const short8*)(xT + (size_t)n * (XH * XW * CIN));
    const short8* w3v = (const short8*)w3;

    // ---- in-flight gather state: ONE item = 16 VGPR + 2 scalars -----------
    U8 st0, st1, st2, st3;
    int gd = 0, pp = 0;

    auto ISSUE = [&](int kk, int i) {
        int idx = i * 512 + tid;
        int chg = idx & 31;
        int pos = idx >> 5;
        pp = kk * 64 + pos;
        ushort4 ov = pairO[pp];
        st0.s = xTv[(size_t)((int)ov.x * 32 + chg)];
        st1.s = xTv[(size_t)((int)ov.y * 32 + chg)];
        st2.s = xTv[(size_t)((int)ov.z * 32 + chg)];
        st3.s = xTv[(size_t)((int)ov.w * 32 + chg)];
        gd = chg * 64 + (pos ^ (chg & 7));
    };
    auto FINISH = [&](short* dst) {
        floatx4 wv = pairW[pp];
        U8 pk;
#pragma unroll
        for (int i = 0; i < 4; ++i) {
            floatx2 v = bf16x2_to_f32x2(st0.u[i]) * wv.x
                      + bf16x2_to_f32x2(st1.u[i]) * wv.y
                      + bf16x2_to_f32x2(st2.u[i]) * wv.z
                      + bf16x2_to_f32x2(st3.u[i]) * wv.w;
            float2 ff; ff.x = v.x; ff.y = v.y;
            __hip_bfloat162 hb = __float22bfloat162_rn(ff);
            __builtin_memcpy(&pk.u[i], &hb, 4);
        }
        *(short8*)&dst[gd * 8] = pk.s;
    };
    auto KS = [&](int k, int ks, const short8* cb) {
        short8 afrag[2];
#pragma unroll
        for (int mt = 0; mt < 2; ++mt)
            afrag[mt] = w3v[(((k * 8 + ks) * 16) + (wave * 2 + mt)) * 64 + lane];
        short8 bfrag[4];
        int cr = ks * 4 + quad;
        int gb = cr * 64, sw = cr & 7;
#pragma unroll
        for (int nt = 0; nt < 4; ++nt)
            bfrag[nt] = cb[gb + ((nt * 16 + cl) ^ sw)];
#pragma unroll
        for (int mt = 0; mt < 2; ++mt)
#pragma unroll
            for (int nt = 0; nt < 4; ++nt)
                acc[mt][nt] = __builtin_amdgcn_mfma_f32_16x16x32_bf16(
                    afrag[mt], bfrag[nt], acc[mt][nt], 0, 0, 0);
    };
    auto tapStep = [&](int k, const short* curp, short* nxtp, bool pre) {
        const short8* cb = (const short8*)curp;
        if (pre) ISSUE(k + 1, 0);
        KS(k, 0, cb); KS(k, 1, cb);
        if (pre) { FINISH(nxtp); ISSUE(k + 1, 1); }
        KS(k, 2, cb); KS(k, 3, cb);
        if (pre) { FINISH(nxtp); ISSUE(k + 1, 2); }
        KS(k, 4, cb); KS(k, 5, cb);
        if (pre) { FINISH(nxtp); ISSUE(k + 1, 3); }
        KS(k, 6, cb); KS(k, 7, cb);
        if (pre) { FINISH(nxtp); __syncthreads(); }
    };

    // ---- prologue: sample tap 0 into colF[0] ----
    for (int i = 0; i < 4; ++i) { ISSUE(0, i); FINISH(colF[0]); }
    __syncthreads();

    // ---- 9 taps, ping-pong buffers with compile-time pointers ----
#pragma unroll 1
    for (int kp = 0; kp < 4; ++kp) {
        tapStep(2 * kp,     colF[0], colF[1], true);
        tapStep(2 * kp + 1, colF[1], colF[0], true);
    }
    tapStep(8, colF[0], colF[1], false);

    // ---- epilogue: D layout col=lane&15 (pos), row=(lane>>4)*4+reg (co) ----
#pragma unroll
    for (int mt = 0; mt < 2; ++mt) {
        int cobase = (wave * 2 + mt) * 16 + quad * 4;
#pragma unroll
        for (int r = 0; r < 4; ++r) {
            int co = cobase + r;
            float b = bias[co];
            float* op = out + (((size_t)n * COUT + co) * XH + ho) * XW;
#pragma unroll
            for (int nt = 0; nt < 4; ++nt)
                op[nt * 16 + cl] = acc[mt][nt][r] + b;
        }
    }
}

// ===========================================================================
// Fallback 1 (ws in [1.18MB, 18MB)): round-1 fused kernel (NCHW gathers).
__global__ void dcn_wprep_v1(const float* __restrict__ w, short* __restrict__ w3) {
    int idx = blockIdx.x * 256 + threadIdx.x;
    if (idx >= 8 * 9 * 16 * 64 * 8) return;
    int j    = idx & 7;
    int lane = (idx >> 3) & 63;
    int mt   = (idx >> 9) & 15;
    int t    = idx >> 13;
    int ks   = t % 9;
    int cc   = t / 9;
    int co = mt * 16 + (lane & 15);
    int c  = cc * 32 + (lane >> 4) * 8 + j;
    w3[idx] = f32_to_bf16_rne(w[(co * CIN + c) * NK + ks]);
}

__launch_bounds__(256, 2)
__global__ void dcn_fused_v1(const float* __restrict__ x,
                             const float* __restrict__ off,
                             const float* __restrict__ msk,
                             const short* __restrict__ w3,
                             const float* __restrict__ bias,
                             float* __restrict__ out) {
    __shared__ short  colF[2304 * 8];
    __shared__ floatx4 pairW[576];
    __shared__ intx4   pairO[576];

    const int bid = blockIdx.x;
    const int n  = bid >> 6;
    const int ho = bid & 63;
    const int tid  = threadIdx.x;
    const int wave = tid >> 6;
    const int lane = tid & 63;

    for (int p = tid; p < 576; p += 256) {
        int wo = p & 63, k = p >> 6;
        int obase = ((n * 18 + 2 * k) * XH + ho) * XW + wo;
        float dy = off[obase];
        float dx = off[obase + XH * XW];
        float mm = msk[((n * NK + k) * XH + ho) * XW + wo];
        float y  = (float)(ho - 1 + k / 3) + dy;
        float xs = (float)(wo - 1 + k % 3) + dx;
        float y0f = floorf(y), x0f = floorf(xs);
        float fy = y - y0f, fx = xs - x0f;
        int y0 = (int)y0f, x0 = (int)x0f;
        float vy0 = (y0 >= 0  && y0 < XH)     ? 1.f : 0.f;
        float vy1 = (y0 >= -1 && y0 < XH - 1) ? 1.f : 0.f;
        float vx0 = (x0 >= 0  && x0 < XW)     ? 1.f : 0.f;
        float vx1 = (x0 >= -1 && x0 < XW - 1) ? 1.f : 0.f;
        floatx4 wv;
        wv.x = (1.f - fy) * (1.f - fx) * mm * vy0 * vx0;
        wv.y = (1.f - fy) * fx         * mm * vy0 * vx1;
        wv.z = fy         * (1.f - fx) * mm * vy1 * vx0;
        wv.w = fy         * fx         * mm * vy1 * vx1;
        int y0c = min(max(y0, 0), XH - 1), y1c = min(max(y0 + 1, 0), XH - 1);
        int x0c = min(max(x0, 0), XW - 1), x1c = min(max(x0 + 1, 0), XW - 1);
        intx4 ov;
        ov.x = y0c * XW + x0c; ov.y = y0c * XW + x1c;
        ov.z = y1c * XW + x0c; ov.w = y1c * XW + x1c;
        pairW[p] = wv;
        pairO[p] = ov;
    }
    __syncthreads();

    floatx4 acc[4][4];
#pragma unroll
    for (int mt = 0; mt < 4; ++mt)
#pragma unroll
        for (int nt = 0; nt < 4; ++nt)
            acc[mt][nt] = (floatx4)(0.f);

    const float* xn = x + (size_t)n * CIN * (XH * XW);
    const short8* w3v = (const short8*)w3;

    for (int cc = 0; cc < 8; ++cc) {
        __syncthreads();
        for (int it = 0; it < 9; ++it) {
            int item = it * 256 + tid;
            int pos  = item & 63;
            int r    = item >> 6;
            int k    = r >> 2;
            int csub = r & 3;
            int p = k * 64 + pos;
            floatx4 wv = pairW[p];
            intx4   ov = pairO[p];
            const float* xc = xn + (size_t)(cc * 32 + csub * 8) * (XH * XW);
            short8 pk;
#pragma unroll
            for (int i = 0; i < 8; ++i) {
                const float* xp = xc + i * (XH * XW);
                float v = wv.x * xp[ov.x] + wv.y * xp[ov.y] +
                          wv.z * xp[ov.z] + wv.w * xp[ov.w];
                pk[i] = f32_to_bf16_rne(v);
            }
            *(short8*)&colF[(((k * 4 + csub) * 64) + pos) * 8] = pk;
        }
        __syncthreads();

        const int quad = lane >> 4, cl = lane & 15;
        for (int ks = 0; ks < 9; ++ks) {
            short8 afrag[4];
#pragma unroll
            for (int mt = 0; mt < 4; ++mt) {
                int mtg = wave * 4 + mt;
                afrag[mt] = w3v[(((cc * 9 + ks) * 16 + mtg) * 64) + lane];
            }
            short8 bfrag[4];
#pragma unroll
            for (int nt = 0; nt < 4; ++nt)
                bfrag[nt] = *(const short8*)
                    &colF[(((ks * 4 + quad) * 64) + nt * 16 + cl) * 8];
#pragma unroll
            for (int mt = 0; mt < 4; ++mt)
#pragma unroll
                for (int nt = 0; nt < 4; ++nt)
                    acc[mt][nt] = __builtin_amdgcn_mfma_f32_16x16x32_bf16(
                        afrag[mt], bfrag[nt], acc[mt][nt], 0, 0, 0);
        }
    }

    const int quad = lane >> 4, cl = lane & 15;
#pragma unroll
    for (int mt = 0; mt < 4; ++mt) {
        int cobase = (wave * 4 + mt) * 16 + quad * 4;
#pragma unroll
        for (int r = 0; r < 4; ++r) {
            int co = cobase + r;
            float b = bias[co];
            float* op = out + (((size_t)n * COUT + co) * XH + ho) * XW;
#pragma unroll
            for (int nt = 0; nt < 4; ++nt)
                op[nt * 16 + cl] = acc[mt][nt][r] + b;
        }
    }
}

// Fallback 2: naive (ws < 1.18MB).
__global__ void dcn_naive(const float* __restrict__ x,
                          const float* __restrict__ off,
                          const float* __restrict__ msk,
                          const float* __restrict__ w,
                          const float* __restrict__ bias,
                          float* __restrict__ out) {
    int idx = blockIdx.x * 256 + threadIdx.x;
    if (idx >= 8 * COUT * XH * XW) return;
    int wo = idx & 63, ho = (idx >> 6) & 63, co = (idx >> 12) & 255, n = idx >> 20;
    float acc = bias[co];
    for (int k = 0; k < NK; ++k) {
        int obase = ((n * 18 + 2 * k) * XH + ho) * XW + wo;
        float dy = off[obase];
        float dx = off[obase + XH * XW];
        float mm = msk[((n * NK + k) * XH + ho) * XW + wo];
        float y  = (float)(ho - 1 + k / 3) + dy;
        float xs = (float)(wo - 1 + k % 3) + dx;
        float y0f = floorf(y), x0f = floorf(xs);
        float fy = y - y0f, fx = xs - x0f;
        int y0 = (int)y0f, x0 = (int)x0f;
        float vy0 = (y0 >= 0  && y0 < XH)     ? 1.f : 0.f;
        float vy1 = (y0 >= -1 && y0 < XH - 1) ? 1.f : 0.f;
        float vx0 = (x0 >= 0  && x0 < XW)     ? 1.f : 0.f;
        float vx1 = (x0 >= -1 && x0 < XW - 1) ? 1.f : 0.f;
        float w00 = (1.f - fy) * (1.f - fx) * mm * vy0 * vx0;
        float w01 = (1.f - fy) * fx         * mm * vy0 * vx1;
        float w10 = fy         * (1.f - fx) * mm * vy1 * vx0;
        float w11 = fy         * fx         * mm * vy1 * vx1;
        int y0c = min(max(y0, 0), XH - 1), y1c = min(max(y0 + 1, 0), XH - 1);
        int x0c = min(max(x0, 0), XW - 1), x1c = min(max(x0 + 1, 0), XW - 1);
        int o00 = y0c * XW + x0c, o01 = y0c * XW + x1c;
        int o10 = y1c * XW + x0c, o11 = y1c * XW + x1c;
        for (int c = 0; c < CIN; ++c) {
            const float* xp = x + ((size_t)(n * CIN + c)) * (XH * XW);
            float v = w00 * xp[o00] + w01 * xp[o01] + w10 * xp[o10] + w11 * xp[o11];
            acc += v * w[(co * CIN + c) * NK + k];
        }
    }
    out[idx] = acc;
}

// ---------------------------------------------------------------------------
extern "C" void kernel_launch(void* const* d_in, const int* in_sizes, int n_in,
                              void* d_out, int out_size, void* d_ws, size_t ws_size,
                              hipStream_t stream) {
    const float* x    = (const float*)d_in[0];
    const float* off  = (const float*)d_in[1];
    const float* msk  = (const float*)d_in[2];
    const float* w    = (const float*)d_in[3];
    const float* bias = (const float*)d_in[4];
    float* out = (float*)d_out;

    const size_t W3_BYTES = (size_t)9 * 8 * 16 * 64 * 8 * sizeof(short); // 1179648
    const size_t XT_BYTES = (size_t)8 * XH * XW * CIN * sizeof(short);   // 16777216

    if (ws_size >= W3_BYTES + XT_BYTES) {
        short* w3 = (short*)d_ws;
        short* xT = (short*)((char*)d_ws + W3_BYTES);
        dcn_prep<<<512 + 288, 256, 0, stream>>>(x, w, xT, w3);
        dcn_fused7<<<8 * 64, 512, 0, stream>>>(xT, off, msk, w3, bias, out);
    } else if (ws_size >= W3_BYTES) {
        short* w3 = (short*)d_ws;
        dcn_wprep_v1<<<(8 * 9 * 16 * 64 * 8 + 255) / 256, 256, 0, stream>>>(w, w3);
        dcn_fused_v1<<<8 * 64, 256, 0, stream>>>(x, off, msk, w3, bias, out);
    } else {
        dcn_naive<<<(8 * COUT * XH * XW + 255) / 256, 256, 0, stream>>>(
            x, off, msk, w, bias, out);
    }
}

// Round 5
// 148.475 us; speedup vs baseline: 1.9681x; 1.1574x over previous
//
#include <hip/hip_runtime.h>
#include <hip/hip_bf16.h>
#include <stdint.h>

// DCNv2 forward, fixed shapes: N=8, Cin=Cout=256, H=W=Ho=Wo=64, K=3x3, DG=1,
// stride=1, pad=1, dil=1.
//
// R8: R3 schedule (the 67.6us best: phaseA | barrier | phaseB | barrier,
// single colF buffer) + direct VALU cuts. Session ledger:
//   R4/R7 (reg-stage across MFMA, 1-4 items): spills at the unified reg cap
//       (WRITE_SIZE +17..43MB scratch). NO register state may cross MFMA.
//   R5 (same-wave dbuf, 1 barrier): barrier re-aligns waves; no overlap; slower.
//   R6 (producer/consumer waves): regalloc is static -> producers carry dead
//       acc AGPRs, spill; also 4-way LDS write conflicts from adjacent-chg
//       pairing (even-only XOR coverage).
// R8 changes (no schedule change):
//   1. Paired gathers (chg, chg+16): one pairO read + one addr chain per 8
//      corner loads (2nd granule = +256B immediate). Stride-16 keeps full
//      0..7 XOR coverage on ds_writes -> 0 conflicts (unlike R6).
//   2. Phase-B addressing hoisted: swizzle has only 2 per-ks variants
//      (parity), precomputed; afrag pointer strength-reduced.
//   3. s_setprio(1) around MFMA cluster (2 co-resident blocks slip
//      independently -> T5's favorable regime).

#define XH 64
#define XW 64
#define CIN 256
#define COUT 256
#define NK 9

typedef __attribute__((ext_vector_type(8))) short short8;   // 8 bf16 (4 VGPRs)
typedef __attribute__((ext_vector_type(4))) float floatx4;
typedef __attribute__((ext_vector_type(2))) float floatx2;
typedef __attribute__((ext_vector_type(4))) int   intx4;

__device__ __forceinline__ short f32_to_bf16_rne(float f) {
    union { float f; uint32_t u; } v; v.f = f;
    uint32_t u = v.u;
    uint32_t r = (u + 0x7FFFu + ((u >> 16) & 1u)) >> 16;
    return (short)(uint16_t)r;
}
__device__ __forceinline__ float bf16_to_f32(short s) {
    union { uint32_t u; float f; } v;
    v.u = ((uint32_t)(uint16_t)s) << 16;
    return v.f;
}
__device__ __forceinline__ floatx2 bf16x2_to_f32x2(uint32_t u) {
    union { uint32_t u; float f; } lo, hi;
    lo.u = u << 16;
    hi.u = u & 0xFFFF0000u;
    floatx2 r; r.x = lo.f; r.y = hi.f;
    return r;
}

union U8 { short8 s; uint32_t u[4]; };

// ---------------------------------------------------------------------------
// Combined prep (unchanged from R3).
// Blocks [0,512): x (N,C,H,W) f32 -> xT (N,H,W,C) bf16, XCD-swizzled so the
//   XCD that writes rows [8x,8x+8) is the one that reads them in dcn_fused8.
// Blocks [512,800): weight swizzle -> w3 (bf16), 8 elems/thread.
__global__ void dcn_prep(const float* __restrict__ x, const float* __restrict__ w,
                         short* __restrict__ xT, short* __restrict__ w3) {
    int b = blockIdx.x;
    int tid = threadIdx.x;
    if (b < 512) {
        int xcd = b & 7, slot = b >> 3;
        int h = xcd * 8 + (slot & 7);
        int n = slot >> 3;
        int q = tid & 15;        // w-quad
        int cgh = tid >> 4;      // 0..15
        short8* ob = (short8*)(xT + ((size_t)(n * XH + h)) * (XW * CIN));
        for (int it = 0; it < 2; ++it) {
            int cg = cgh + it * 16;          // channel granule 0..31
            const float* xb = x + ((size_t)(n * CIN + cg * 8)) * (XH * XW)
                                + h * XW + q * 4;
            floatx4 r[8];
#pragma unroll
            for (int j = 0; j < 8; ++j)
                r[j] = *(const floatx4*)(xb + (size_t)j * (XH * XW));
#pragma unroll
            for (int jw = 0; jw < 4; ++jw) {
                short8 pk;
#pragma unroll
                for (int j = 0; j < 8; ++j) pk[j] = f32_to_bf16_rne(r[j][jw]);
                ob[(q * 4 + jw) * 32 + cg] = pk;
            }
        }
    } else {
        int gidx = (b - 512) * 256 + tid;    // granule index, < 73728
        int lane = gidx & 63;
        int mt   = (gidx >> 6) & 15;
        int t    = gidx >> 10;               // k*8 + ks
        int ks   = t & 7;
        int k    = t >> 3;
        int co = mt * 16 + (lane & 15);
        int c0 = ks * 32 + (lane >> 4) * 8;
        short8 pk;
#pragma unroll
        for (int j = 0; j < 8; ++j)
            pk[j] = f32_to_bf16_rne(w[(co * CIN + c0 + j) * NK + k]);
        *(short8*)&w3[(size_t)gidx * 8] = pk;
    }
}

// ---------------------------------------------------------------------------
// Fused kernel. grid = N*Ho = 512, 512 threads (8 waves), XCD-swizzled.
// Per tap: phase A (paired gathers -> colF) | barrier | phase B (8 MFMA
// K-steps) | barrier.
__launch_bounds__(512, 4)
__global__ void dcn_fused8(const short* __restrict__ xT,
                           const float* __restrict__ off,
                           const float* __restrict__ msk,
                           const short* __restrict__ w3,
                           const float* __restrict__ bias,
                           float* __restrict__ out) {
    // colF: 2048 granules of 16B. granule(chg,pos) at g = chg*64+(pos^(chg&7))
    __shared__ short   colF[2048 * 8];       // 32768 B
    __shared__ floatx4 pairW[576];           //  9216 B
    __shared__ ushort4 pairO[576];           //  4608 B (raw spatial offs)

    const int bid = blockIdx.x;
    const int xcd = bid & 7, slot = bid >> 3;
    const int ho = xcd * 8 + (slot & 7);     // XCD x owns ho band [8x, 8x+8)
    const int n  = slot >> 3;
    const int tid  = threadIdx.x;
    const int wave = tid >> 6;
    const int lane = tid & 63;
    const int quad = lane >> 4, cl = lane & 15;

    // ---- bilinear params for 576 (wo, tap) pairs (mask folded into weights).
    for (int p = tid; p < 576; p += 512) {
        int wo = p & 63, k = p >> 6;
        int obase = ((n * 18 + 2 * k) * XH + ho) * XW + wo;
        float dy = off[obase];
        float dx = off[obase + XH * XW];
        float mm = msk[((n * NK + k) * XH + ho) * XW + wo];
        float y  = (float)(ho - 1 + k / 3) + dy;
        float xs = (float)(wo - 1 + k % 3) + dx;
        float y0f = floorf(y), x0f = floorf(xs);
        float fy = y - y0f, fx = xs - x0f;
        int y0 = (int)y0f, x0 = (int)x0f;
        float vy0 = (y0 >= 0  && y0 < XH)     ? 1.f : 0.f;
        float vy1 = (y0 >= -1 && y0 < XH - 1) ? 1.f : 0.f;
        float vx0 = (x0 >= 0  && x0 < XW)     ? 1.f : 0.f;
        float vx1 = (x0 >= -1 && x0 < XW - 1) ? 1.f : 0.f;
        floatx4 wv;
        wv.x = (1.f - fy) * (1.f - fx) * mm * vy0 * vx0;
        wv.y = (1.f - fy) * fx         * mm * vy0 * vx1;
        wv.z = fy         * (1.f - fx) * mm * vy1 * vx0;
        wv.w = fy         * fx         * mm * vy1 * vx1;
        int y0c = min(max(y0, 0), XH - 1), y1c = min(max(y0 + 1, 0), XH - 1);
        int x0c = min(max(x0, 0), XW - 1), x1c = min(max(x0 + 1, 0), XW - 1);
        ushort4 ov;
        ov.x = (unsigned short)(y0c * XW + x0c);
        ov.y = (unsigned short)(y0c * XW + x1c);
        ov.z = (unsigned short)(y1c * XW + x0c);
        ov.w = (unsigned short)(y1c * XW + x1c);
        pairW[p] = wv;
        pairO[p] = ov;
    }
    __syncthreads();

    floatx4 acc[2][4];
#pragma unroll
    for (int mt = 0; mt < 2; ++mt)
#pragma unroll
        for (int nt = 0; nt < 4; ++nt)
            acc[mt][nt] = (floatx4)(0.f);

    const short8* xTv = (const short8*)(xT + (size_t)n * (XH * XW * CIN));
    const short8* w3v = (const short8*)w3;

    // ---- phase-B address hoists: swizzle has only 2 per-ks variants -------
    int boffE[4], boffO[4];
#pragma unroll
    for (int nt = 0; nt < 4; ++nt) {
        boffE[nt] = (nt * 16 + cl) ^ quad;         // ks even: sw = quad
        boffO[nt] = ((nt * 16 + cl) ^ quad) ^ 4;   // ks odd:  sw = quad^4
    }
    const short8* cbase = (const short8*)colF;

    // ---- phase A: paired gathers (chg, chg+16). 1024 pairs, 2 per thread.
    // Lane pattern: cp = lane&15 -> 16 lanes x 16B = 256B contiguous per
    // (pos, corner); 2nd granule at +256B folds into the load offset.
    // ds_writes keep full 0..7 XOR coverage -> 0 bank conflicts (R6 lesson).
    auto sampleTap = [&](int k) {
        for (int it = 0; it < 2; ++it) {
            int pidx = it * 512 + tid;
            int cp  = pidx & 15;
            int pos = pidx >> 4;
            int p = k * 64 + pos;
            ushort4 ov = pairO[p];
            const short8* q00 = xTv + ((int)ov.x * 32 + cp);
            const short8* q01 = xTv + ((int)ov.y * 32 + cp);
            const short8* q10 = xTv + ((int)ov.z * 32 + cp);
            const short8* q11 = xTv + ((int)ov.w * 32 + cp);
            U8 a0, b0, c0, d0, a1, b1, c1, d1;
            a0.s = q00[0]; a1.s = q00[16];
            b0.s = q01[0]; b1.s = q01[16];
            c0.s = q10[0]; c1.s = q10[16];
            d0.s = q11[0]; d1.s = q11[16];
            floatx4 wv = pairW[p];
            U8 pk0, pk1;
#pragma unroll
            for (int i = 0; i < 4; ++i) {
                floatx2 v0 = bf16x2_to_f32x2(a0.u[i]) * wv.x
                           + bf16x2_to_f32x2(b0.u[i]) * wv.y
                           + bf16x2_to_f32x2(c0.u[i]) * wv.z
                           + bf16x2_to_f32x2(d0.u[i]) * wv.w;
                floatx2 v1 = bf16x2_to_f32x2(a1.u[i]) * wv.x
                           + bf16x2_to_f32x2(b1.u[i]) * wv.y
                           + bf16x2_to_f32x2(c1.u[i]) * wv.z
                           + bf16x2_to_f32x2(d1.u[i]) * wv.w;
                float2 f0; f0.x = v0.x; f0.y = v0.y;
                float2 f1; f1.x = v1.x; f1.y = v1.y;
                __hip_bfloat162 h0 = __float22bfloat162_rn(f0);
                __hip_bfloat162 h1 = __float22bfloat162_rn(f1);
                __builtin_memcpy(&pk0.u[i], &h0, 4);
                __builtin_memcpy(&pk1.u[i], &h1, 4);
            }
            int sw = pos ^ (cp & 7);
            *(short8*)&colF[(cp * 64 + sw) * 8] = pk0.s;
            *(short8*)&colF[((cp + 16) * 64 + sw) * 8] = pk1.s;
        }
    };

    // ---- prologue: tap 0 ----
    sampleTap(0);

#pragma unroll 1
    for (int k = 0; k < NK; ++k) {
        __syncthreads();                       // phase A of tap k complete

        // ---- phase B: 8 K-steps of 32 channels ----
        __builtin_amdgcn_s_setprio(1);
        const short8* ap = w3v + ((k * 8 * 16) + wave * 2) * 64 + lane;
#pragma unroll
        for (int ks = 0; ks < 8; ++ks) {
            short8 afrag0 = ap[0];
            short8 afrag1 = ap[64];
            const short8* cb = cbase + (ks * 256 + quad * 64);
            short8 bfrag[4];
#pragma unroll
            for (int nt = 0; nt < 4; ++nt)
                bfrag[nt] = cb[(ks & 1) ? boffO[nt] : boffE[nt]];
#pragma unroll
            for (int nt = 0; nt < 4; ++nt)
                acc[0][nt] = __builtin_amdgcn_mfma_f32_16x16x32_bf16(
                    afrag0, bfrag[nt], acc[0][nt], 0, 0, 0);
#pragma unroll
            for (int nt = 0; nt < 4; ++nt)
                acc[1][nt] = __builtin_amdgcn_mfma_f32_16x16x32_bf16(
                    afrag1, bfrag[nt], acc[1][nt], 0, 0, 0);
            ap += 16 * 64;
        }
        __builtin_amdgcn_s_setprio(0);

        if (k < NK - 1) {
            __syncthreads();                   // phase B done reading colF
            sampleTap(k + 1);
        }
    }

    // ---- epilogue: D layout col=lane&15 (pos), row=(lane>>4)*4+reg (co) ----
#pragma unroll
    for (int mt = 0; mt < 2; ++mt) {
        int cobase = (wave * 2 + mt) * 16 + quad * 4;
#pragma unroll
        for (int r = 0; r < 4; ++r) {
            int co = cobase + r;
            float b = bias[co];
            float* op = out + (((size_t)n * COUT + co) * XH + ho) * XW;
#pragma unroll
            for (int nt = 0; nt < 4; ++nt)
                op[nt * 16 + cl] = acc[mt][nt][r] + b;
        }
    }
}

// ===========================================================================
// Fallback 1 (ws in [1.18MB, 18MB)): round-1 fused kernel (NCHW gathers).
__global__ void dcn_wprep_v1(const float* __restrict__ w, short* __restrict__ w3) {
    int idx = blockIdx.x * 256 + threadIdx.x;
    if (idx >= 8 * 9 * 16 * 64 * 8) return;
    int j    = idx & 7;
    int lane = (idx >> 3) & 63;
    int mt   = (idx >> 9) & 15;
    int t    = idx >> 13;
    int ks   = t % 9;
    int cc   = t / 9;
    int co = mt * 16 + (lane & 15);
    int c  = cc * 32 + (lane >> 4) * 8 + j;
    w3[idx] = f32_to_bf16_rne(w[(co * CIN + c) * NK + ks]);
}

__launch_bounds__(256, 2)
__global__ void dcn_fused_v1(const float* __restrict__ x,
                             const float* __restrict__ off,
                             const float* __restrict__ msk,
                             const short* __restrict__ w3,
                             const float* __restrict__ bias,
                             float* __restrict__ out) {
    __shared__ short  colF[2304 * 8];
    __shared__ floatx4 pairW[576];
    __shared__ intx4   pairO[576];

    const int bid = blockIdx.x;
    const int n  = bid >> 6;
    const int ho = bid & 63;
    const int tid  = threadIdx.x;
    const int wave = tid >> 6;
    const int lane = tid & 63;

    for (int p = tid; p < 576; p += 256) {
        int wo = p & 63, k = p >> 6;
        int obase = ((n * 18 + 2 * k) * XH + ho) * XW + wo;
        float dy = off[obase];
        float dx = off[obase + XH * XW];
        float mm = msk[((n * NK + k) * XH + ho) * XW + wo];
        float y  = (float)(ho - 1 + k / 3) + dy;
        float xs = (float)(wo - 1 + k % 3) + dx;
        float y0f = floorf(y), x0f = floorf(xs);
        float fy = y - y0f, fx = xs - x0f;
        int y0 = (int)y0f, x0 = (int)x0f;
        float vy0 = (y0 >= 0  && y0 < XH)     ? 1.f : 0.f;
        float vy1 = (y0 >= -1 && y0 < XH - 1) ? 1.f : 0.f;
        float vx0 = (x0 >= 0  && x0 < XW)     ? 1.f : 0.f;
        float vx1 = (x0 >= -1 && x0 < XW - 1) ? 1.f : 0.f;
        floatx4 wv;
        wv.x = (1.f - fy) * (1.f - fx) * mm * vy0 * vx0;
        wv.y = (1.f - fy) * fx         * mm * vy0 * vx1;
        wv.z = fy         * (1.f - fx) * mm * vy1 * vx0;
        wv.w = fy         * fx         * mm * vy1 * vx1;
        int y0c = min(max(y0, 0), XH - 1), y1c = min(max(y0 + 1, 0), XH - 1);
        int x0c = min(max(x0, 0), XW - 1), x1c = min(max(x0 + 1, 0), XW - 1);
        intx4 ov;
        ov.x = y0c * XW + x0c; ov.y = y0c * XW + x1c;
        ov.z = y1c * XW + x0c; ov.w = y1c * XW + x1c;
        pairW[p] = wv;
        pairO[p] = ov;
    }
    __syncthreads();

    floatx4 acc[4][4];
#pragma unroll
    for (int mt = 0; mt < 4; ++mt)
#pragma unroll
        for (int nt = 0; nt < 4; ++nt)
            acc[mt][nt] = (floatx4)(0.f);

    const float* xn = x + (size_t)n * CIN * (XH * XW);
    const short8* w3v = (const short8*)w3;

    for (int cc = 0; cc < 8; ++cc) {
        __syncthreads();
        for (int it = 0; it < 9; ++it) {
            int item = it * 256 + tid;
            int pos  = item & 63;
            int r    = item >> 6;
            int k    = r >> 2;
            int csub = r & 3;
            int p = k * 64 + pos;
            floatx4 wv = pairW[p];
            intx4   ov = pairO[p];
            const float* xc = xn + (size_t)(cc * 32 + csub * 8) * (XH * XW);
            short8 pk;
#pragma unroll
            for (int i = 0; i < 8; ++i) {
                const float* xp = xc + i * (XH * XW);
                float v = wv.x * xp[ov.x] + wv.y * xp[ov.y] +
                          wv.z * xp[ov.z] + wv.w * xp[ov.w];
                pk[i] = f32_to_bf16_rne(v);
            }
            *(short8*)&colF[(((k * 4 + csub) * 64) + pos) * 8] = pk;
        }
        __syncthreads();

        const int quad = lane >> 4, cl = lane & 15;
        for (int ks = 0; ks < 9; ++ks) {
            short8 afrag[4];
#pragma unroll
            for (int mt = 0; mt < 4; ++mt) {
                int mtg = wave * 4 + mt;
                afrag[mt] = w3v[(((cc * 9 + ks) * 16 + mtg) * 64) + lane];
            }
            short8 bfrag[4];
#pragma unroll
            for (int nt = 0; nt < 4; ++nt)
                bfrag[nt] = *(const short8*)
                    &colF[(((ks * 4 + quad) * 64) + nt * 16 + cl) * 8];
#pragma unroll
            for (int mt = 0; mt < 4; ++mt)
#pragma unroll
                for (int nt = 0; nt < 4; ++nt)
                    acc[mt][nt] = __builtin_amdgcn_mfma_f32_16x16x32_bf16(
                        afrag[mt], bfrag[nt], acc[mt][nt], 0, 0, 0);
        }
    }

    const int quad = lane >> 4, cl = lane & 15;
#pragma unroll
    for (int mt = 0; mt < 4; ++mt) {
        int cobase = (wave * 4 + mt) * 16 + quad * 4;
#pragma unroll
        for (int r = 0; r < 4; ++r) {
            int co = cobase + r;
            float b = bias[co];
            float* op = out + (((size_t)n * COUT + co) * XH + ho) * XW;
#pragma unroll
            for (int nt = 0; nt < 4; ++nt)
                op[nt * 16 + cl] = acc[mt][nt][r] + b;
        }
    }
}

// Fallback 2: naive (ws < 1.18MB).
__global__ void dcn_naive(const float* __restrict__ x,
                          const float* __restrict__ off,
                          const float* __restrict__ msk,
                          const float* __restrict__ w,
                          const float* __restrict__ bias,
                          float* __restrict__ out) {
    int idx = blockIdx.x * 256 + threadIdx.x;
    if (idx >= 8 * COUT * XH * XW) return;
    int wo = idx & 63, ho = (idx >> 6) & 63, co = (idx >> 12) & 255, n = idx >> 20;
    float acc = bias[co];
    for (int k = 0; k < NK; ++k) {
        int obase = ((n * 18 + 2 * k) * XH + ho) * XW + wo;
        float dy = off[obase];
        float dx = off[obase + XH * XW];
        float mm = msk[((n * NK + k) * XH + ho) * XW + wo];
        float y  = (float)(ho - 1 + k / 3) + dy;
        float xs = (float)(wo - 1 + k % 3) + dx;
        float y0f = floorf(y), x0f = floorf(xs);
        float fy = y - y0f, fx = xs - x0f;
        int y0 = (int)y0f, x0 = (int)x0f;
        float vy0 = (y0 >= 0  && y0 < XH)     ? 1.f : 0.f;
        float vy1 = (y0 >= -1 && y0 < XH - 1) ? 1.f : 0.f;
        float vx0 = (x0 >= 0  && x0 < XW)     ? 1.f : 0.f;
        float vx1 = (x0 >= -1 && x0 < XW - 1) ? 1.f : 0.f;
        float w00 = (1.f - fy) * (1.f - fx) * mm * vy0 * vx0;
        float w01 = (1.f - fy) * fx         * mm * vy0 * vx1;
        float w10 = fy         * (1.f - fx) * mm * vy1 * vx0;
        float w11 = fy         * fx         * mm * vy1 * vx1;
        int y0c = min(max(y0, 0), XH - 1), y1c = min(max(y0 + 1, 0), XH - 1);
        int x0c = min(max(x0, 0), XW - 1), x1c = min(max(x0 + 1, 0), XW - 1);
        int o00 = y0c * XW + x0c, o01 = y0c * XW + x1c;
        int o10 = y1c * XW + x0c, o11 = y1c * XW + x1c;
        for (int c = 0; c < CIN; ++c) {
            const float* xp = x + ((size_t)(n * CIN + c)) * (XH * XW);
            float v = w00 * xp[o00] + w01 * xp[o01] + w10 * xp[o10] + w11 * xp[o11];
            acc += v * w[(co * CIN + c) * NK + k];
        }
    }
    out[idx] = acc;
}

// ---------------------------------------------------------------------------
extern "C" void kernel_launch(void* const* d_in, const int* in_sizes, int n_in,
                              void* d_out, int out_size, void* d_ws, size_t ws_size,
                              hipStream_t stream) {
    const float* x    = (const float*)d_in[0];
    const float* off  = (const float*)d_in[1];
    const float* msk  = (const float*)d_in[2];
    const float* w    = (const float*)d_in[3];
    const float* bias = (const float*)d_in[4];
    float* out = (float*)d_out;

    const size_t W3_BYTES = (size_t)9 * 8 * 16 * 64 * 8 * sizeof(short); // 1179648
    const size_t XT_BYTES = (size_t)8 * XH * XW * CIN * sizeof(short);   // 16777216

    if (ws_size >= W3_BYTES + XT_BYTES) {
        short* w3 = (short*)d_ws;
        short* xT = (short*)((char*)d_ws + W3_BYTES);
        dcn_prep<<<512 + 288, 256, 0, stream>>>(x, w, xT, w3);
        dcn_fused8<<<8 * 64, 512, 0, stream>>>(xT, off, msk, w3, bias, out);
    } else if (ws_size >= W3_BYTES) {
        short* w3 = (short*)d_ws;
        dcn_wprep_v1<<<(8 * 9 * 16 * 64 * 8 + 255) / 256, 256, 0, stream>>>(w, w3);
        dcn_fused_v1<<<8 * 64, 256, 0, stream>>>(x, off, msk, w3, bias, out);
    } else {
        dcn_naive<<<(8 * COUT * XH * XW + 255) / 256, 256, 0, stream>>>(
            x, off, msk, w, bias, out);
    }
}